// Round 14
// baseline (186.471 us; speedup 1.0000x reference)
//
#include <hip/hip_runtime.h>

// LogicGateNetwork: fused gather-net + dead-neuron elimination.
// R14: build chain (memset + mark + 4x assign + build = 7 dispatches, mostly
// launch-gap overhead) collapsed into ONE 64-block kernel with atomic-counter
// grid barriers (64 blocks <= 256 CUs -> co-resident, safe device barrier).
// Fused kernel unchanged from R13 (2 rows/block, half2 LDS, 72KB -> 2 blk/CU).
// LDS region plan (half2 entries, 18432 = 72KB):
//   x:[0,8192) -> L0:[8192,+n0) -> L1:[0,n1) -> L2:[8192,+n2) -> L3:[0,n3)
// Bounds: n3<=2000, n2<=4000, n1<=8000<8192, n0<=10240 (actual ~8031).

#define NBATCH 2048
#define IN_DIM 8192
#define HID 16384
#define OUT_DIM 1000
#define LDS_ENT 18432          // half2 entries = 73728 B
#define MARKV 0x7FFFFFFF

typedef __attribute__((ext_vector_type(4))) _Float16 half4;
typedef __attribute__((ext_vector_type(2))) _Float16 half2v;

__device__ __constant__ float GC_dev[64] = {
    0, 0, 0, 0,   0, 0, 0, 1,   0, 1, 0, -1,  0, 1, 0, 0,
    0, 0, 1, -1,  0, 0, 1, 0,   0, 1, 1, -2,  0, 1, 1, -1,
    1, -1, -1, 1, 1, -1, -1, 2, 1, 0, -1, 0,  1, 0, -1, 1,
    1, -1, 0, 0,  1, -1, 0, 1,  1, 0, 0, -1,  1, 0, 0, 0
};

struct Tabs {
    const float* w[5];
    const int* ia[5];
    const int* ib[5];
};

// softmax(w_row) @ GATE_COEF -> half4
__device__ __forceinline__ half4 coef_of(const float* __restrict__ wrow) {
    float v[16];
    const float4* w4 = (const float4*)wrow;
#pragma unroll
    for (int i = 0; i < 4; ++i) {
        float4 t = w4[i];
        v[4*i+0] = t.x; v[4*i+1] = t.y; v[4*i+2] = t.z; v[4*i+3] = t.w;
    }
    float m = v[0];
#pragma unroll
    for (int g = 1; g < 16; ++g) m = fmaxf(m, v[g]);
    float s = 0.f;
#pragma unroll
    for (int g = 0; g < 16; ++g) { v[g] = __expf(v[g] - m); s += v[g]; }
    float inv = 1.f / s;
    float c0 = 0.f, c1 = 0.f, c2 = 0.f, c3 = 0.f;
#pragma unroll
    for (int g = 0; g < 16; ++g) {
        c0 += v[g] * GC_dev[g*4+0];
        c1 += v[g] * GC_dev[g*4+1];
        c2 += v[g] * GC_dev[g*4+2];
        c3 += v[g] * GC_dev[g*4+3];
    }
    half4 c;
    c[0] = (_Float16)(c0*inv); c[1] = (_Float16)(c1*inv);
    c[2] = (_Float16)(c2*inv); c[3] = (_Float16)(c3*inv);
    return c;
}

// Grid barrier for a 64-block co-resident kernel. Monotone counter; after
// phase p every block has added 1, so spin until bar >= 64*p.
__device__ __forceinline__ void gridbar(int* bar, int target) {
    __syncthreads();
    if (threadIdx.x == 0) {
        __threadfence();
        __hip_atomic_fetch_add(bar, 1, __ATOMIC_ACQ_REL, __HIP_MEMORY_SCOPE_AGENT);
        while (__hip_atomic_load(bar, __ATOMIC_ACQUIRE, __HIP_MEMORY_SCOPE_AGENT) < target) {
            __builtin_amdgcn_s_sleep(1);
        }
        __threadfence();
    }
    __syncthreads();
}

// ONE kernel: maps init -> mark -> assign/mark x4 -> build tables (+inline
// softmax coefs for live neurons only). grid = 64 x 256 (covers HID exactly).
// header[0..3]=live counts, header[8]=barrier counter (pre-zeroed by memset).
__global__ __launch_bounds__(256) void super_build_kernel(
    Tabs args, int* __restrict__ maps, int* __restrict__ header,
    unsigned int* __restrict__ tabIdx, half4* __restrict__ tabCoef) {
    int i = blockIdx.x * 256 + threadIdx.x;   // 0..16383
    int* map0 = maps, *map1 = maps + HID, *map2 = maps + 2*HID, *map3 = maps + 3*HID;
    int* bar = header + 8;

    // phase 0: init maps
    map0[i] = -1; map1[i] = -1; map2[i] = -1; map3[i] = -1;
    gridbar(bar, 64);

    // phase 1: output layer marks live layer-3 neurons
    if (i < OUT_DIM) { map3[args.ia[4][i]] = MARKV; map3[args.ib[4][i]] = MARKV; }
    gridbar(bar, 128);

    // phases 2..5: assign slots for layer l, mark parents in layer l-1
    if (map3[i] == MARKV) {
        map3[i] = atomicAdd(header + 3, 1);
        map2[args.ia[3][i]] = MARKV; map2[args.ib[3][i]] = MARKV;
    }
    gridbar(bar, 192);
    if (map2[i] == MARKV) {
        map2[i] = atomicAdd(header + 2, 1);
        map1[args.ia[2][i]] = MARKV; map1[args.ib[2][i]] = MARKV;
    }
    gridbar(bar, 256);
    if (map1[i] == MARKV) {
        map1[i] = atomicAdd(header + 1, 1);
        map0[args.ia[1][i]] = MARKV; map0[args.ib[1][i]] = MARKV;
    }
    gridbar(bar, 320);
    if (map0[i] == MARKV) {
        map0[i] = atomicAdd(header + 0, 1);
    }
    gridbar(bar, 384);

    // phase 6: build all 5 compact tables (parent bases compile-time 0/8192)
    if (i < OUT_DIM) {   // output layer: parents in L3 region (base 0)
        unsigned a = (unsigned)map3[args.ia[4][i]];
        unsigned b = (unsigned)map3[args.ib[4][i]];
        tabIdx[4*HID + i] = a | (b << 16);
        tabCoef[4*HID + i] = coef_of(args.w[4] + (size_t)i * 16);
    }
    int s3 = map3[i];
    if (s3 >= 0) {       // layer 3: parents in L2 region (base 8192)
        unsigned a = 8192u + (unsigned)map2[args.ia[3][i]];
        unsigned b = 8192u + (unsigned)map2[args.ib[3][i]];
        tabIdx[3*HID + s3] = a | (b << 16);
        tabCoef[3*HID + s3] = coef_of(args.w[3] + (size_t)i * 16);
    }
    int s2 = map2[i];
    if (s2 >= 0) {       // layer 2: parents in L1 region (base 0)
        unsigned a = (unsigned)map1[args.ia[2][i]];
        unsigned b = (unsigned)map1[args.ib[2][i]];
        tabIdx[2*HID + s2] = a | (b << 16);
        tabCoef[2*HID + s2] = coef_of(args.w[2] + (size_t)i * 16);
    }
    int s1 = map1[i];
    if (s1 >= 0) {       // layer 1: parents in L0 region (base 8192)
        unsigned a = 8192u + (unsigned)map0[args.ia[1][i]];
        unsigned b = 8192u + (unsigned)map0[args.ib[1][i]];
        tabIdx[1*HID + s1] = a | (b << 16);
        tabCoef[1*HID + s1] = coef_of(args.w[1] + (size_t)i * 16);
    }
    int s0 = map0[i];
    if (s0 >= 0) {       // layer 0: parents are raw input features (base 0)
        tabIdx[0*HID + s0] =
            (unsigned)args.ia[0][i] | ((unsigned)args.ib[0][i] << 16);
        tabCoef[0*HID + s0] = coef_of(args.w[0] + (size_t)i * 16);
    }
}

__device__ __forceinline__ void layer_pass(
    half2v* lds, const unsigned* __restrict__ tIdx,
    const half4* __restrict__ tCoef, int n, int wbase, int t) {
    for (int j = t; j < n; j += 1024) {
        unsigned idx = tIdx[j];
        half4 c = tCoef[j];
        half2v pa = lds[idx & 0xFFFFu];
        half2v pb = lds[idx >> 16];
        float c0 = (float)c[0], c1 = (float)c[1];
        float c2 = (float)c[2], c3 = (float)c[3];
        float a0 = (float)pa[0], a1 = (float)pa[1];
        float q0 = (float)pb[0], q1 = (float)pb[1];
        half2v o;
        o[0] = (_Float16)fmaf(fmaf(c3, q0, c1), a0, fmaf(c2, q0, c0));
        o[1] = (_Float16)fmaf(fmaf(c3, q1, c1), a1, fmaf(c2, q1, c0));
        lds[wbase + j] = o;
    }
    __syncthreads();
}

// Block bp owns batch rows 2bp, 2bp+1. 72KB dynamic LDS -> 2 blocks/CU.
__global__ __launch_bounds__(1024) void fused_kernel(
    const float* __restrict__ x, const unsigned* __restrict__ tabIdx,
    const half4* __restrict__ tabCoef, const int* __restrict__ header,
    float* __restrict__ out) {
    extern __shared__ half2v lds[];
    int bp = blockIdx.x;
    int t = threadIdx.x;  // 0..1023
    int b0 = 2 * bp, b1 = 2 * bp + 1;
    int n0 = header[0], n1 = header[1], n2 = header[2], n3 = header[3];

    // Stage x rows b0,b1 (fp32 16B/lane coalesced) -> entries [0,8192).
    const float4* xr0 = (const float4*)(x + (size_t)b0 * IN_DIM);
    const float4* xr1 = (const float4*)(x + (size_t)b1 * IN_DIM);
#pragma unroll
    for (int i = 0; i < 2; ++i) {
        int e = i * 1024 + t;
        float4 v0 = xr0[e];
        float4 v1 = xr1[e];
        half2v h0; h0[0] = (_Float16)v0.x; h0[1] = (_Float16)v1.x;
        half2v h1; h1[0] = (_Float16)v0.y; h1[1] = (_Float16)v1.y;
        half2v h2; h2[0] = (_Float16)v0.z; h2[1] = (_Float16)v1.z;
        half2v h3; h3[0] = (_Float16)v0.w; h3[1] = (_Float16)v1.w;
        lds[4*e+0] = h0; lds[4*e+1] = h1; lds[4*e+2] = h2; lds[4*e+3] = h3;
    }
    __syncthreads();

    layer_pass(lds, tabIdx + 0*HID, tabCoef + 0*HID, n0, 8192, t);  // x  -> L0
    layer_pass(lds, tabIdx + 1*HID, tabCoef + 1*HID, n1, 0,    t);  // L0 -> L1
    layer_pass(lds, tabIdx + 2*HID, tabCoef + 2*HID, n2, 8192, t);  // L1 -> L2
    layer_pass(lds, tabIdx + 3*HID, tabCoef + 3*HID, n3, 0,    t);  // L2 -> L3

    if (t < OUT_DIM) {   // output layer reads L3 at base 0
        unsigned idx = tabIdx[4*HID + t];
        half4 c = tabCoef[4*HID + t];
        half2v pa = lds[idx & 0xFFFFu];
        half2v pb = lds[idx >> 16];
        float c0 = (float)c[0], c1 = (float)c[1];
        float c2 = (float)c[2], c3 = (float)c[3];
        float a0 = (float)pa[0], a1 = (float)pa[1];
        float q0 = (float)pb[0], q1 = (float)pb[1];
        out[(size_t)b0 * OUT_DIM + t] = fmaf(fmaf(c3, q0, c1), a0, fmaf(c2, q0, c0));
        out[(size_t)b1 * OUT_DIM + t] = fmaf(fmaf(c3, q1, c1), a1, fmaf(c2, q1, c0));
    }
}

extern "C" void kernel_launch(void* const* d_in, const int* in_sizes, int n_in,
                              void* d_out, int out_size, void* d_ws, size_t ws_size,
                              hipStream_t stream) {
    Tabs args;
    const float* x = (const float*)d_in[0];
    for (int i = 0; i < 5; ++i) {
        args.w[i]  = (const float*)d_in[1 + 3 * i];
        args.ia[i] = (const int*)d_in[2 + 3 * i];
        args.ib[i] = (const int*)d_in[3 + 3 * i];
    }

    // ws layout: maps[4] (4*HID*4B) | header (64B: counts[0..3], bar[8]) |
    //            tabIdx (5*HID*4B) | tabCoef (5*HID*8B)
    char* ws = (char*)d_ws;
    int* maps = (int*)ws;                                             // 262144 B
    int* header = (int*)(ws + 4 * HID * 4);                           // 64 B
    unsigned int* tabIdx = (unsigned int*)(ws + 4*HID*4 + 64);        // 327680 B
    half4* tabCoef = (half4*)(ws + 4*HID*4 + 64 + 5*HID*4);           // 655360 B

    hipMemsetAsync(header, 0, 64, stream);   // counters + barrier word
    super_build_kernel<<<64, 256, 0, stream>>>(args, maps, header, tabIdx, tabCoef);
    fused_kernel<<<NBATCH / 2, 1024, LDS_ENT * sizeof(half2v), stream>>>(
        x, tabIdx, tabCoef, header, (float*)d_out);
}